// Round 7
// baseline (392.282 us; speedup 1.0000x reference)
//
#include <hip/hip_runtime.h>
#include <hip/hip_bf16.h>

#define Bc 16
#define Nn 4096
#define Cc 128
#define Ee 12288
#define Mm 64
#define NEG_SLOPE 0.2f
#define MARGIN 4.2f

typedef __attribute__((ext_vector_type(8))) short bfrag;   // 8 bf16 = 4 VGPR
typedef __attribute__((ext_vector_type(4))) float f32x4;   // MFMA accumulator

__device__ inline unsigned short f2bf_rne(float f) {
    unsigned u = __float_as_uint(f);
    unsigned r = u + 0x7FFFu + ((u >> 16) & 1u);
    return (unsigned short)(r >> 16);
}
__device__ inline float bfbits2f(unsigned short h) {
    return __uint_as_float(((unsigned)h) << 16);
}
// split f32 -> bf16 hi (trunc) + bf16 lo (rne of residual); validated in r6 gemm
__device__ inline void split1(float f, unsigned short& h, unsigned short& lo) {
    unsigned u = __float_as_uint(f);
    unsigned hb = u & 0xFFFF0000u;
    float r = f - __uint_as_float(hb);
    unsigned ru = __float_as_uint(r);
    ru += 0x7FFFu + ((ru >> 16) & 1u);
    h = (unsigned short)(u >> 16);
    lo = (unsigned short)(ru >> 16);
}
__device__ inline void split8(const float* f, bfrag& h, bfrag& l) {
#pragma unroll
    for (int j = 0; j < 8; ++j) {
        unsigned short hh, ll;
        split1(f[j], hh, ll);
        h[j] = (short)hh; l[j] = (short)ll;
    }
}

// ---------------- prep: wsplit (blocks 0-63) + hist/Acnt (blocks 64-111) -------------
// wsplit layout: row=col c (256B of 128 bf16 k's), byte = 2k ^ ((c&7)<<4).
__global__ __launch_bounds__(256) void prep_kernel(const float* __restrict__ w,
                                                   const int* __restrict__ nodes,
                                                   const int* __restrict__ edges,
                                                   unsigned short* __restrict__ wsplit,
                                                   int* __restrict__ deg_n,
                                                   int* __restrict__ deg_m,
                                                   float* __restrict__ Acnt) {
    int blk = blockIdx.x, t = threadIdx.x;
    if (blk < 64) {
        int idx = blk * 256 + t;  // 16384 = 128*128
        int k = idx >> 7, c = idx & 127;
        float v = w[k * 128 + c];
        unsigned short h, lo;
        split1(v, h, lo);
        // NOTE: hi here must be RNE to match r6? r6 used rne for h in wsplit; keep split1
        // (trunc-hi + rne-lo is a valid exact split: h+lo+eps == v to 2^-17 rel)
        int byteoff = c * 256 + ((2 * k) ^ ((c & 7) << 4));
        *(unsigned short*)((char*)wsplit + byteoff) = h;
        *(unsigned short*)((char*)wsplit + 32768 + byteoff) = lo;
    } else {
        int e = (blk - 64) * 256 + t;  // 12288 = 48*256
        int n = nodes[e], m = edges[e];
        atomicAdd(&deg_n[n], 1);
        atomicAdd(&deg_m[m], 1);
        atomicAdd(&Acnt[m * 4096 + n], 1.0f);
    }
}

// ---------------- GEMM via bf16 split MFMA: xwT = (x @ w)^T as bf16 hi/lo -------------
// Writes xwT_h/xwT_l [2048 slots][4096 n] (slot = b*128+c), plus p[n][b], S1[n].
__global__ __launch_bounds__(256) void gemm_xw(const float* __restrict__ x,
                                               const unsigned short* __restrict__ wsplit,
                                               const float* __restrict__ att,
                                               unsigned short* __restrict__ xwTh,
                                               unsigned short* __restrict__ xwTl,
                                               float* __restrict__ p,
                                               float* __restrict__ S1) {
    __shared__ unsigned short wlds[32768];  // 64KB: whT_swz | wlT_swz
    int t = threadIdx.x;
    {
        const float4* g4 = (const float4*)wsplit;
        float4* l4 = (float4*)wlds;
#pragma unroll
        for (int i = 0; i < 16; ++i) l4[i * 256 + t] = g4[i * 256 + t];
    }
    __syncthreads();

    int w = t >> 6, l = t & 63;
    int lrow = l & 15, lk = l >> 4;
    int rowbase = blockIdx.x * 128 + w * 32;

    f32x4 acc[2][8];
#pragma unroll
    for (int ti = 0; ti < 2; ++ti)
#pragma unroll
        for (int tj = 0; tj < 8; ++tj) acc[ti][tj] = (f32x4){0.f, 0.f, 0.f, 0.f};

    for (int ks = 0; ks < 4; ++ks) {
        bfrag bh[8], bl[8];
        int kbyte = (64 * ks + 16 * lk) ^ ((l & 7) << 4);
#pragma unroll
        for (int tj = 0; tj < 8; ++tj) {
            const char* base = (const char*)wlds + (tj * 16 + lrow) * 256 + kbyte;
            bh[tj] = *(const bfrag*)base;
            bl[tj] = *(const bfrag*)(base + 32768);
        }
#pragma unroll
        for (int ti = 0; ti < 2; ++ti) {
            int row = rowbase + ti * 16 + lrow;
            const float4* xp = (const float4*)(x + (size_t)row * 128 + ks * 32 + lk * 8);
            float4 v0 = xp[0], v1 = xp[1];
            float fa[8] = {v0.x, v0.y, v0.z, v0.w, v1.x, v1.y, v1.z, v1.w};
            bfrag ah, al;
#pragma unroll
            for (int j = 0; j < 8; ++j) {
                unsigned short hh, ll;
                split1(fa[j], hh, ll);
                ah[j] = (short)hh; al[j] = (short)ll;
            }
#pragma unroll
            for (int tj = 0; tj < 8; ++tj) {
                acc[ti][tj] = __builtin_amdgcn_mfma_f32_16x16x32_bf16(ah, bh[tj], acc[ti][tj], 0, 0, 0);
                acc[ti][tj] = __builtin_amdgcn_mfma_f32_16x16x32_bf16(ah, bl[tj], acc[ti][tj], 0, 0, 0);
                acc[ti][tj] = __builtin_amdgcn_mfma_f32_16x16x32_bf16(al, bh[tj], acc[ti][tj], 0, 0, 0);
            }
        }
    }

    // epilogue A: xwT packed bf16 hi/lo writes (ushort4 = 4 consecutive n per lane)
#pragma unroll
    for (int ti = 0; ti < 2; ++ti) {
#pragma unroll
        for (int tj = 0; tj < 8; ++tj) {
            int rr0 = rowbase + ti * 16 + lk * 4;
            int b = rr0 >> 12, n0 = rr0 & 4095;
            int slot = b * 128 + tj * 16 + lrow;
            ushort4 hv, lv;
            split1(acc[ti][tj][0], hv.x, lv.x);
            split1(acc[ti][tj][1], hv.y, lv.y);
            split1(acc[ti][tj][2], hv.z, lv.z);
            split1(acc[ti][tj][3], hv.w, lv.w);
            *(ushort4*)(xwTh + (size_t)slot * 4096 + n0) = hv;
            *(ushort4*)(xwTl + (size_t)slot * 4096 + n0) = lv;
        }
    }
    // epilogue B: p / S1 (full f32 precision)
    float aw_[8];
#pragma unroll
    for (int tj = 0; tj < 8; ++tj) aw_[tj] = att[tj * 16 + lrow];
#pragma unroll
    for (int ti = 0; ti < 2; ++ti) {
#pragma unroll
        for (int v = 0; v < 4; ++v) {
            int rr = rowbase + ti * 16 + lk * 4 + v;
            int b = rr >> 12, n = rr & 4095;
            float pd = 0.f, ss = 0.f;
#pragma unroll
            for (int tj = 0; tj < 8; ++tj) {
                float val = acc[ti][tj][v];
                pd += val * aw_[tj];
                ss += val;
            }
#pragma unroll
            for (int m = 1; m < 16; m <<= 1) {
                pd += __shfl_xor(pd, m, 64);
                ss += __shfl_xor(ss, m, 64);
            }
            if (lrow == 0) {
                p[n * 16 + b] = pd;
                atomicAdd(&S1[n], ss);
            }
        }
    }
}

// ---------------- exclusive scan (node side only) ----------------
__global__ __launch_bounds__(1024) void scan_kernel(const int* __restrict__ deg_n,
                                                    int* __restrict__ off_n,
                                                    int* __restrict__ cur_n) {
    __shared__ int s[1024];
    int t = threadIdx.x;
    int base = t * 4;
    int d0 = deg_n[base], d1 = deg_n[base + 1], d2 = deg_n[base + 2], d3 = deg_n[base + 3];
    int local = d0 + d1 + d2 + d3;
    s[t] = local;
    __syncthreads();
    for (int offs = 1; offs < 1024; offs <<= 1) {
        int v = (t >= offs) ? s[t - offs] : 0;
        __syncthreads();
        s[t] += v;
        __syncthreads();
    }
    int excl = s[t] - local;
    int o0 = excl, o1 = excl + d0, o2 = excl + d0 + d1, o3 = excl + d0 + d1 + d2;
    off_n[base] = o0; off_n[base + 1] = o1; off_n[base + 2] = o2; off_n[base + 3] = o3;
    cur_n[base] = o0; cur_n[base + 1] = o1; cur_n[base + 2] = o2; cur_n[base + 3] = o3;
    if (t == 1023) off_n[4096] = s[1023];
}

// ---------------- fill node-CSR: gedge_n[pos] = hyperedge id ----------------
__global__ void fill_kernel(const int* __restrict__ nodes, const int* __restrict__ edges,
                            int* __restrict__ cur_n, int* __restrict__ gedge_n) {
    int e = blockIdx.x * 256 + threadIdx.x;
    if (e < Ee) {
        int pos = atomicAdd(&cur_n[nodes[e]], 1);
        gedge_n[pos] = edges[e];
    }
}

// ---------------- es GEMM: es[m][slot] = sum_n Acnt[m][n]*xwT[slot][n]; fused q,T ------
// grid 32 (slot-blocks of 64); block 256 = 4 waves; wave = m-tile w x 4 slot-tiles.
__global__ __launch_bounds__(256) void es_gemm(const float* __restrict__ Acnt,
                                               const unsigned short* __restrict__ xwTh,
                                               const unsigned short* __restrict__ xwTl,
                                               const float* __restrict__ att,
                                               float* __restrict__ es,
                                               float* __restrict__ q,
                                               float* __restrict__ T) {
    int t = threadIdx.x, w = t >> 6, l = t & 63;
    int lrow = l & 15, lk = l >> 4;
    int slot0 = blockIdx.x * 64;
    f32x4 acc[4];
#pragma unroll
    for (int tj = 0; tj < 4; ++tj) acc[tj] = (f32x4){0.f, 0.f, 0.f, 0.f};
    const float* arow = Acnt + (size_t)(w * 16 + lrow) * 4096;
#pragma unroll 2
    for (int ks = 0; ks < 128; ++ks) {
        int n0 = ks * 32 + lk * 8;
        const float* ap = arow + n0;
        bfrag af;
#pragma unroll
        for (int j = 0; j < 8; ++j) af[j] = (short)(__float_as_uint(ap[j]) >> 16);  // counts exact
#pragma unroll
        for (int tj = 0; tj < 4; ++tj) {
            size_t off = (size_t)(slot0 + tj * 16 + lrow) * 4096 + n0;
            bfrag bh = *(const bfrag*)(xwTh + off);
            bfrag bl = *(const bfrag*)(xwTl + off);
            acc[tj] = __builtin_amdgcn_mfma_f32_16x16x32_bf16(af, bh, acc[tj], 0, 0, 0);
            acc[tj] = __builtin_amdgcn_mfma_f32_16x16x32_bf16(af, bl, acc[tj], 0, 0, 0);
        }
    }
    int b = slot0 >> 7;
    float qp[4] = {0, 0, 0, 0}, tp[4] = {0, 0, 0, 0};
#pragma unroll
    for (int tj = 0; tj < 4; ++tj) {
        int slot = slot0 + tj * 16 + lrow;
        float a2 = att[128 + (slot & 127)];
#pragma unroll
        for (int reg = 0; reg < 4; ++reg) {
            int mm = w * 16 + lk * 4 + reg;
            float val = acc[tj][reg];
            es[mm * 2048 + slot] = val;
            qp[reg] += val * a2;
            tp[reg] += val;
        }
    }
#pragma unroll
    for (int msk = 1; msk < 16; msk <<= 1) {
#pragma unroll
        for (int reg = 0; reg < 4; ++reg) {
            qp[reg] += __shfl_xor(qp[reg], msk, 64);
            tp[reg] += __shfl_xor(tp[reg], msk, 64);
        }
    }
    if (lrow == 0) {
#pragma unroll
        for (int reg = 0; reg < 4; ++reg) {
            int mm = w * 16 + lk * 4 + reg;
            atomicAdd(&q[mm * 16 + b], qp[reg]);
            atomicAdd(&T[mm], tp[reg]);
        }
    }
}

// ---------------- pairwise hyperedge loss (norms inline) ----------------
__global__ __launch_bounds__(256) void loss_kernel(const float* __restrict__ es,
                                                   float* __restrict__ loss_part) {
    int m = blockIdx.x, t = threadIdx.x;
    __shared__ float esm[2048];
    __shared__ float sml[16];
    for (int i = t; i < 2048; i += 256) esm[i] = es[m * 2048 + i];
    __syncthreads();
    if (t < 16) {
        float s = 0.f;
        const float* r = esm + t * 128;
        for (int c = 0; c < 128; ++c) s += r[c] * r[c];
        sml[t] = s;
    }
    __syncthreads();
    int n = t >> 2, bq = t & 3;
    float part = 0.f;
#pragma unroll
    for (int u = 0; u < 4; u++) {
        int b = bq * 4 + u;
        float inner = 0.f, sn = 0.f;
        const float* er = es + n * 2048 + b * 128;
        const float* em = esm + b * 128;
        for (int c = 0; c < 128; c += 4) {
            float4 a = *(const float4*)(em + c);
            float4 o = *(const float4*)(er + c);
            inner += a.x * o.x + a.y * o.y + a.z * o.z + a.w * o.w;
            sn += o.x * o.x + o.y * o.y + o.z * o.z + o.w * o.w;
        }
        float sm = sml[b];
        float cosv = inner / (sqrtf(sm) * sqrtf(sn));
        float d2 = sm + sn - 2.f * inner;
        float dist = sqrtf(fmaxf(d2, 0.f));
        part += cosv * dist + (1.f - cosv) * fmaxf(MARGIN - dist, 0.f);
    }
    part += __shfl_xor(part, 1, 64);
    part += __shfl_xor(part, 2, 64);
    float labs = fabsf(part * (1.f / 16.f));
    __shared__ float pl[64];
    if (bq == 0) pl[n] = labs;
    __syncthreads();
    if (t < 64) {
        float v = pl[t];
        for (int k = 1; k < 64; k <<= 1) v += __shfl_xor(v, k, 64);
        if (t == 0) loss_part[m] = v;
    }
}

// ---------------- alpha softmax + Wa/Wb scatter (alpha array eliminated) --------------
// Wa[b][m][n] += alpha ; Wb[b][n][m] += alpha/deg_m[m]
__global__ __launch_bounds__(256) void alpha_wab(const int* __restrict__ off_n,
                                                 const int* __restrict__ gedge_n,
                                                 const float* __restrict__ p,
                                                 const float* __restrict__ q,
                                                 const int* __restrict__ deg_m,
                                                 float* __restrict__ Wa,
                                                 float* __restrict__ Wb) {
    int idx = blockIdx.x * 256 + threadIdx.x;  // 65536 = N*B
    int b = idx & 15, n = idx >> 4;
    int beg = off_n[n], end = off_n[n + 1];
    if (beg == end) return;
    float pb = p[n * 16 + b];
    float lf = pb + q[gedge_n[beg] * 16 + b];
    lf = lf >= 0.f ? lf : NEG_SLOPE * lf;
    float ssum = 0.f;
    for (int i = beg; i < end; i++) {
        float lg = pb + q[gedge_n[i] * 16 + b];
        lg = lg >= 0.f ? lg : NEG_SLOPE * lg;
        ssum += __expf(lg - lf);
    }
    float inv = 1.f / ssum;
    for (int i = beg; i < end; i++) {
        int m = gedge_n[i];
        float lg = pb + q[m * 16 + b];
        lg = lg >= 0.f ? lg : NEG_SLOPE * lg;
        float a = __expf(lg - lf) * inv;
        float bninv = 1.f / (float)deg_m[m];
        atomicAdd(&Wa[((size_t)b * 64 + m) * 4096 + n], a);
        atomicAdd(&Wb[((size_t)b * 4096 + n) * 64 + m], a * bninv);
    }
}

// ---------------- ouT GEMM: ouT[slot][m] = sum_n xwT[slot][n]*Wa[b][m][n] -------------
// grid (32 slot-blocks, 4 k-chunks); atomic accumulate (ouT zeroed).
__global__ __launch_bounds__(256) void oute_gemm(const unsigned short* __restrict__ xwTh,
                                                 const unsigned short* __restrict__ xwTl,
                                                 const float* __restrict__ Wa,
                                                 float* __restrict__ ouT) {
    int t = threadIdx.x, w = t >> 6, l = t & 63;
    int lrow = l & 15, lk = l >> 4;
    int slot0 = blockIdx.x * 64;
    int b = slot0 >> 7;
    int kbase = blockIdx.y * 1024;
    f32x4 acc[4];
#pragma unroll
    for (int tj = 0; tj < 4; ++tj) acc[tj] = (f32x4){0.f, 0.f, 0.f, 0.f};
    int srow = slot0 + w * 16 + lrow;
    const unsigned short* xh = xwTh + (size_t)srow * 4096;
    const unsigned short* xl = xwTl + (size_t)srow * 4096;
    const float* wab = Wa + (size_t)b * 64 * 4096;
#pragma unroll 2
    for (int ks = 0; ks < 32; ++ks) {
        int n0 = kbase + ks * 32 + lk * 8;
        bfrag ah = *(const bfrag*)(xh + n0);
        bfrag al = *(const bfrag*)(xl + n0);
#pragma unroll
        for (int tj = 0; tj < 4; ++tj) {
            int mcol = tj * 16 + lrow;
            bfrag wh, wl_;
            split8(wab + (size_t)mcol * 4096 + n0, wh, wl_);
            acc[tj] = __builtin_amdgcn_mfma_f32_16x16x32_bf16(ah, wh, acc[tj], 0, 0, 0);
            acc[tj] = __builtin_amdgcn_mfma_f32_16x16x32_bf16(ah, wl_, acc[tj], 0, 0, 0);
            acc[tj] = __builtin_amdgcn_mfma_f32_16x16x32_bf16(al, wh, acc[tj], 0, 0, 0);
        }
    }
#pragma unroll
    for (int tj = 0; tj < 4; ++tj) {
        int mcol = tj * 16 + lrow;
#pragma unroll
        for (int reg = 0; reg < 4; ++reg) {
            int slot = slot0 + w * 16 + lk * 4 + reg;
            atomicAdd(&ouT[slot * 64 + mcol], acc[tj][reg]);
        }
    }
}

// ---------------- out GEMM: out[b][n][c] = D[n]*sum_m Wb[b][n][m]*ouT[b*128+c][m] -----
// grid (32 n-blocks, 16 b); K=64; direct store.
__global__ __launch_bounds__(256) void out_gemm(const float* __restrict__ Wb,
                                                const float* __restrict__ ouT,
                                                const int* __restrict__ deg_n,
                                                float* __restrict__ out) {
    int t = threadIdx.x, w = t >> 6, l = t & 63;
    int lrow = l & 15, lk = l >> 4;
    int nbase = blockIdx.x * 128 + w * 32;
    int b = blockIdx.y;
    f32x4 acc[2][8];
#pragma unroll
    for (int ti = 0; ti < 2; ++ti)
#pragma unroll
        for (int tj = 0; tj < 8; ++tj) acc[ti][tj] = (f32x4){0.f, 0.f, 0.f, 0.f};
#pragma unroll
    for (int ks = 0; ks < 2; ++ks) {
        int m0 = ks * 32 + lk * 8;
        bfrag wh[2], wl[2];
#pragma unroll
        for (int ti = 0; ti < 2; ++ti) {
            int nr = nbase + ti * 16 + lrow;
            split8(Wb + ((size_t)b * 4096 + nr) * 64 + m0, wh[ti], wl[ti]);
        }
#pragma unroll
        for (int tj = 0; tj < 8; ++tj) {
            int slot = b * 128 + tj * 16 + lrow;
            bfrag oh, ol;
            split8(ouT + (size_t)slot * 64 + m0, oh, ol);
#pragma unroll
            for (int ti = 0; ti < 2; ++ti) {
                acc[ti][tj] = __builtin_amdgcn_mfma_f32_16x16x32_bf16(wh[ti], oh, acc[ti][tj], 0, 0, 0);
                acc[ti][tj] = __builtin_amdgcn_mfma_f32_16x16x32_bf16(wh[ti], ol, acc[ti][tj], 0, 0, 0);
                acc[ti][tj] = __builtin_amdgcn_mfma_f32_16x16x32_bf16(wl[ti], oh, acc[ti][tj], 0, 0, 0);
            }
        }
    }
#pragma unroll
    for (int ti = 0; ti < 2; ++ti) {
#pragma unroll
        for (int reg = 0; reg < 4; ++reg) {
            int n = nbase + ti * 16 + lk * 4 + reg;
            float d = (float)deg_n[n];
#pragma unroll
            for (int tj = 0; tj < 8; ++tj) {
                out[(size_t)b * 524288 + (size_t)n * 128 + tj * 16 + lrow] = d * acc[ti][tj][reg];
            }
        }
    }
}

// ---------------- finalize scalar ----------------
__global__ __launch_bounds__(256) void finalize_kernel(const int* __restrict__ deg_n,
                                                       const float* __restrict__ S1,
                                                       const int* __restrict__ deg_m,
                                                       const float* __restrict__ T,
                                                       const float* __restrict__ loss_part,
                                                       float* __restrict__ out_scalar) {
    int t = threadIdx.x;
    double a = 0.0;
    for (int n = t; n < 4096; n += 256) a += (double)deg_n[n] * (double)S1[n];
    double bsum = 0.0, lsum = 0.0;
    if (t < 64) {
        bsum = (double)deg_m[t] * (double)T[t];
        lsum = (double)loss_part[t];
    }
    __shared__ double sa[256], sb[256], sl[256];
    sa[t] = a; sb[t] = bsum; sl[t] = lsum;
    __syncthreads();
    for (int s = 128; s > 0; s >>= 1) {
        if (t < s) { sa[t] += sa[t + s]; sb[t] += sb[t + s]; sl[t] += sl[t + s]; }
        __syncthreads();
    }
    if (t == 0) {
        double mean = (sa[0] - sb[0]) / 25165824.0;  // E*B*C
        out_scalar[0] = (float)(fabs(mean) + sl[0] / 4225.0);
    }
}

extern "C" void kernel_launch(void* const* d_in, const int* in_sizes, int n_in,
                              void* d_out, int out_size, void* d_ws, size_t ws_size,
                              hipStream_t stream) {
    const float* x = (const float*)d_in[0];
    const int* nodes = (const int*)d_in[1];
    const int* edges = (const int*)d_in[2];
    const float* w = (const float*)d_in[3];
    const float* att = (const float*)d_in[4];
    float* out = (float*)d_out;

    char* ws = (char*)d_ws;
    size_t o = 0;
    unsigned short* xwTh = (unsigned short*)(ws + o); o += (size_t)2048 * 4096 * 2;  // 16 MB
    unsigned short* xwTl = (unsigned short*)(ws + o); o += (size_t)2048 * 4096 * 2;  // 16 MB
    // ---- zero region (one memset): Acnt, Wa, Wb, ouT, deg_n, deg_m, S1, q, T ----
    size_t zbase = o;
    float* Acnt = (float*)(ws + o);  o += (size_t)Mm * Nn * 4;            // 1 MB
    float* Wa = (float*)(ws + o);    o += (size_t)Bc * Mm * Nn * 4;       // 16 MB
    float* Wb = (float*)(ws + o);    o += (size_t)Bc * Nn * Mm * 4;       // 16 MB
    float* ouT = (float*)(ws + o);   o += (size_t)2048 * 64 * 4;          // 512 KB
    int* deg_n = (int*)(ws + o);     o += (size_t)Nn * 4;
    int* deg_m = (int*)(ws + o);     o += (size_t)Mm * 4;
    float* S1 = (float*)(ws + o);    o += (size_t)Nn * 4;
    float* q = (float*)(ws + o);     o += (size_t)Mm * Bc * 4;
    float* T = (float*)(ws + o);     o += (size_t)Mm * 4;
    size_t zlen = o - zbase;
    // ---- end zero region ----
    float* es = (float*)(ws + o);        o += (size_t)Mm * 2048 * 4;      // 512 KB
    float* p = (float*)(ws + o);         o += (size_t)Nn * Bc * 4;        // 256 KB
    float* loss_part = (float*)(ws + o); o += (size_t)Mm * 4;
    int* off_n = (int*)(ws + o);         o += (size_t)(Nn + 1) * 4;
    int* cur_n = (int*)(ws + o);         o += (size_t)Nn * 4;
    int* gedge_n = (int*)(ws + o);       o += (size_t)Ee * 4;
    unsigned short* wsplit = (unsigned short*)(ws + o); o += 65536;       // 64 KB

    hipMemsetAsync(ws + zbase, 0, zlen, stream);

    prep_kernel<<<112, 256, 0, stream>>>(w, nodes, edges, wsplit, deg_n, deg_m, Acnt);
    gemm_xw<<<512, 256, 0, stream>>>(x, wsplit, att, xwTh, xwTl, p, S1);
    scan_kernel<<<1, 1024, 0, stream>>>(deg_n, off_n, cur_n);
    fill_kernel<<<48, 256, 0, stream>>>(nodes, edges, cur_n, gedge_n);
    es_gemm<<<32, 256, 0, stream>>>(Acnt, xwTh, xwTl, att, es, q, T);
    loss_kernel<<<Mm, 256, 0, stream>>>(es, loss_part);
    alpha_wab<<<256, 256, 0, stream>>>(off_n, gedge_n, p, q, deg_m, Wa, Wb);
    oute_gemm<<<dim3(32, 4), 256, 0, stream>>>(xwTh, xwTl, Wa, ouT);
    out_gemm<<<dim3(32, 16), 256, 0, stream>>>(Wb, ouT, deg_n, out);
    finalize_kernel<<<1, 256, 0, stream>>>(deg_n, S1, deg_m, T, loss_part, out + (size_t)Bc * Nn * Cc);
}

// Round 8
// 282.328 us; speedup vs baseline: 1.3895x; 1.3895x over previous
//
#include <hip/hip_runtime.h>
#include <hip/hip_bf16.h>

#define Bc 16
#define Nn 4096
#define Cc 128
#define Ee 12288
#define Mm 64
#define NEG_SLOPE 0.2f
#define MARGIN 4.2f
#define NCH 8  // K-split chunks for es/oute GEMMs (4096/8 = 512 n per chunk)

typedef __attribute__((ext_vector_type(8))) short bfrag;   // 8 bf16 = 4 VGPR
typedef __attribute__((ext_vector_type(4))) float f32x4;   // MFMA accumulator

__device__ inline unsigned short f2bf_rne(float f) {
    unsigned u = __float_as_uint(f);
    unsigned r = u + 0x7FFFu + ((u >> 16) & 1u);
    return (unsigned short)(r >> 16);
}
__device__ inline float bfbits2f(unsigned short h) {
    return __uint_as_float(((unsigned)h) << 16);
}
// split f32 -> bf16 hi (trunc) + bf16 lo (rne of residual)
__device__ inline void split1(float f, unsigned short& h, unsigned short& lo) {
    unsigned u = __float_as_uint(f);
    unsigned hb = u & 0xFFFF0000u;
    float r = f - __uint_as_float(hb);
    unsigned ru = __float_as_uint(r);
    ru += 0x7FFFu + ((ru >> 16) & 1u);
    h = (unsigned short)(u >> 16);
    lo = (unsigned short)(ru >> 16);
}
__device__ inline void split8(const float* f, bfrag& h, bfrag& l) {
#pragma unroll
    for (int j = 0; j < 8; ++j) {
        unsigned short hh, ll;
        split1(f[j], hh, ll);
        h[j] = (short)hh; l[j] = (short)ll;
    }
}

// ---------------- prep: wsplit (blocks 0-63) + hist/Acnt (blocks 64-111) -------------
__global__ __launch_bounds__(256) void prep_kernel(const float* __restrict__ w,
                                                   const int* __restrict__ nodes,
                                                   const int* __restrict__ edges,
                                                   unsigned short* __restrict__ wsplit,
                                                   int* __restrict__ deg_n,
                                                   int* __restrict__ deg_m,
                                                   float* __restrict__ Acnt) {
    int blk = blockIdx.x, t = threadIdx.x;
    if (blk < 64) {
        int idx = blk * 256 + t;  // 16384 = 128*128
        int k = idx >> 7, c = idx & 127;
        float v = w[k * 128 + c];
        unsigned short h, lo;
        split1(v, h, lo);
        int byteoff = c * 256 + ((2 * k) ^ ((c & 7) << 4));
        *(unsigned short*)((char*)wsplit + byteoff) = h;
        *(unsigned short*)((char*)wsplit + 32768 + byteoff) = lo;
    } else {
        int e = (blk - 64) * 256 + t;  // 12288 = 48*256
        int n = nodes[e], m = edges[e];
        atomicAdd(&deg_n[n], 1);
        atomicAdd(&deg_m[m], 1);
        atomicAdd(&Acnt[m * 4096 + n], 1.0f);
    }
}

// ---------------- GEMM via bf16 split MFMA: xwT = (x @ w)^T as bf16 hi/lo -------------
__global__ __launch_bounds__(256) void gemm_xw(const float* __restrict__ x,
                                               const unsigned short* __restrict__ wsplit,
                                               const float* __restrict__ att,
                                               unsigned short* __restrict__ xwTh,
                                               unsigned short* __restrict__ xwTl,
                                               float* __restrict__ p,
                                               float* __restrict__ S1) {
    __shared__ unsigned short wlds[32768];  // 64KB: whT_swz | wlT_swz
    int t = threadIdx.x;
    {
        const float4* g4 = (const float4*)wsplit;
        float4* l4 = (float4*)wlds;
#pragma unroll
        for (int i = 0; i < 16; ++i) l4[i * 256 + t] = g4[i * 256 + t];
    }
    __syncthreads();

    int w = t >> 6, l = t & 63;
    int lrow = l & 15, lk = l >> 4;
    int rowbase = blockIdx.x * 128 + w * 32;

    f32x4 acc[2][8];
#pragma unroll
    for (int ti = 0; ti < 2; ++ti)
#pragma unroll
        for (int tj = 0; tj < 8; ++tj) acc[ti][tj] = (f32x4){0.f, 0.f, 0.f, 0.f};

    for (int ks = 0; ks < 4; ++ks) {
        bfrag bh[8], bl[8];
        int kbyte = (64 * ks + 16 * lk) ^ ((l & 7) << 4);
#pragma unroll
        for (int tj = 0; tj < 8; ++tj) {
            const char* base = (const char*)wlds + (tj * 16 + lrow) * 256 + kbyte;
            bh[tj] = *(const bfrag*)base;
            bl[tj] = *(const bfrag*)(base + 32768);
        }
#pragma unroll
        for (int ti = 0; ti < 2; ++ti) {
            int row = rowbase + ti * 16 + lrow;
            const float4* xp = (const float4*)(x + (size_t)row * 128 + ks * 32 + lk * 8);
            float4 v0 = xp[0], v1 = xp[1];
            float fa[8] = {v0.x, v0.y, v0.z, v0.w, v1.x, v1.y, v1.z, v1.w};
            bfrag ah, al;
#pragma unroll
            for (int j = 0; j < 8; ++j) {
                unsigned short hh, ll;
                split1(fa[j], hh, ll);
                ah[j] = (short)hh; al[j] = (short)ll;
            }
#pragma unroll
            for (int tj = 0; tj < 8; ++tj) {
                acc[ti][tj] = __builtin_amdgcn_mfma_f32_16x16x32_bf16(ah, bh[tj], acc[ti][tj], 0, 0, 0);
                acc[ti][tj] = __builtin_amdgcn_mfma_f32_16x16x32_bf16(ah, bl[tj], acc[ti][tj], 0, 0, 0);
                acc[ti][tj] = __builtin_amdgcn_mfma_f32_16x16x32_bf16(al, bh[tj], acc[ti][tj], 0, 0, 0);
            }
        }
    }

    // epilogue A: xwT packed bf16 hi/lo writes
#pragma unroll
    for (int ti = 0; ti < 2; ++ti) {
#pragma unroll
        for (int tj = 0; tj < 8; ++tj) {
            int rr0 = rowbase + ti * 16 + lk * 4;
            int b = rr0 >> 12, n0 = rr0 & 4095;
            int slot = b * 128 + tj * 16 + lrow;
            ushort4 hv, lv;
            split1(acc[ti][tj][0], hv.x, lv.x);
            split1(acc[ti][tj][1], hv.y, lv.y);
            split1(acc[ti][tj][2], hv.z, lv.z);
            split1(acc[ti][tj][3], hv.w, lv.w);
            *(ushort4*)(xwTh + (size_t)slot * 4096 + n0) = hv;
            *(ushort4*)(xwTl + (size_t)slot * 4096 + n0) = lv;
        }
    }
    // epilogue B: p / S1 (full f32 precision)
    float aw_[8];
#pragma unroll
    for (int tj = 0; tj < 8; ++tj) aw_[tj] = att[tj * 16 + lrow];
#pragma unroll
    for (int ti = 0; ti < 2; ++ti) {
#pragma unroll
        for (int v = 0; v < 4; ++v) {
            int rr = rowbase + ti * 16 + lk * 4 + v;
            int b = rr >> 12, n = rr & 4095;
            float pd = 0.f, ss = 0.f;
#pragma unroll
            for (int tj = 0; tj < 8; ++tj) {
                float val = acc[ti][tj][v];
                pd += val * aw_[tj];
                ss += val;
            }
#pragma unroll
            for (int m = 1; m < 16; m <<= 1) {
                pd += __shfl_xor(pd, m, 64);
                ss += __shfl_xor(ss, m, 64);
            }
            if (lrow == 0) {
                p[n * 16 + b] = pd;
                atomicAdd(&S1[n], ss);
            }
        }
    }
}

// ---------------- exclusive scan (node side only) ----------------
__global__ __launch_bounds__(1024) void scan_kernel(const int* __restrict__ deg_n,
                                                    int* __restrict__ off_n,
                                                    int* __restrict__ cur_n) {
    __shared__ int s[1024];
    int t = threadIdx.x;
    int base = t * 4;
    int d0 = deg_n[base], d1 = deg_n[base + 1], d2 = deg_n[base + 2], d3 = deg_n[base + 3];
    int local = d0 + d1 + d2 + d3;
    s[t] = local;
    __syncthreads();
    for (int offs = 1; offs < 1024; offs <<= 1) {
        int v = (t >= offs) ? s[t - offs] : 0;
        __syncthreads();
        s[t] += v;
        __syncthreads();
    }
    int excl = s[t] - local;
    int o0 = excl, o1 = excl + d0, o2 = excl + d0 + d1, o3 = excl + d0 + d1 + d2;
    off_n[base] = o0; off_n[base + 1] = o1; off_n[base + 2] = o2; off_n[base + 3] = o3;
    cur_n[base] = o0; cur_n[base + 1] = o1; cur_n[base + 2] = o2; cur_n[base + 3] = o3;
    if (t == 1023) off_n[4096] = s[1023];
}

// ---------------- fill node-CSR: gedge_n[pos] = hyperedge id ----------------
__global__ void fill_kernel(const int* __restrict__ nodes, const int* __restrict__ edges,
                            int* __restrict__ cur_n, int* __restrict__ gedge_n) {
    int e = blockIdx.x * 256 + threadIdx.x;
    if (e < Ee) {
        int pos = atomicAdd(&cur_n[nodes[e]], 1);
        gedge_n[pos] = edges[e];
    }
}

// ---------------- es GEMM (K-split): es[m][slot] += sum_{n in chunk} Acnt*xwT ---------
// grid (32 slot-blocks, NCH k-chunks) = 256 blocks; es/q/T atomically accumulated.
__global__ __launch_bounds__(256) void es_gemm(const float* __restrict__ Acnt,
                                               const unsigned short* __restrict__ xwTh,
                                               const unsigned short* __restrict__ xwTl,
                                               const float* __restrict__ att,
                                               float* __restrict__ es,
                                               float* __restrict__ q,
                                               float* __restrict__ T) {
    int t = threadIdx.x, w = t >> 6, l = t & 63;
    int lrow = l & 15, lk = l >> 4;
    int slot0 = blockIdx.x * 64;
    int kbase = blockIdx.y * (4096 / NCH);
    f32x4 acc[4];
#pragma unroll
    for (int tj = 0; tj < 4; ++tj) acc[tj] = (f32x4){0.f, 0.f, 0.f, 0.f};
    const float* arow = Acnt + (size_t)(w * 16 + lrow) * 4096;
#pragma unroll 2
    for (int ks = 0; ks < 4096 / NCH / 32; ++ks) {
        int n0 = kbase + ks * 32 + lk * 8;
        const float* ap = arow + n0;
        bfrag af;
#pragma unroll
        for (int j = 0; j < 8; ++j) af[j] = (short)(__float_as_uint(ap[j]) >> 16);  // counts exact
#pragma unroll
        for (int tj = 0; tj < 4; ++tj) {
            size_t off = (size_t)(slot0 + tj * 16 + lrow) * 4096 + n0;
            bfrag bh = *(const bfrag*)(xwTh + off);
            bfrag bl = *(const bfrag*)(xwTl + off);
            acc[tj] = __builtin_amdgcn_mfma_f32_16x16x32_bf16(af, bh, acc[tj], 0, 0, 0);
            acc[tj] = __builtin_amdgcn_mfma_f32_16x16x32_bf16(af, bl, acc[tj], 0, 0, 0);
        }
    }
    int b = slot0 >> 7;
    float qp[4] = {0, 0, 0, 0}, tp[4] = {0, 0, 0, 0};
#pragma unroll
    for (int tj = 0; tj < 4; ++tj) {
        int slot = slot0 + tj * 16 + lrow;
        float a2 = att[128 + (slot & 127)];
#pragma unroll
        for (int reg = 0; reg < 4; ++reg) {
            int mm = w * 16 + lk * 4 + reg;
            float val = acc[tj][reg];
            atomicAdd(&es[mm * 2048 + slot], val);
            qp[reg] += val * a2;
            tp[reg] += val;
        }
    }
#pragma unroll
    for (int msk = 1; msk < 16; msk <<= 1) {
#pragma unroll
        for (int reg = 0; reg < 4; ++reg) {
            qp[reg] += __shfl_xor(qp[reg], msk, 64);
            tp[reg] += __shfl_xor(tp[reg], msk, 64);
        }
    }
    if (lrow == 0) {
#pragma unroll
        for (int reg = 0; reg < 4; ++reg) {
            int mm = w * 16 + lk * 4 + reg;
            atomicAdd(&q[mm * 16 + b], qp[reg]);
            atomicAdd(&T[mm], tp[reg]);
        }
    }
}

// ---------------- pairwise hyperedge loss (norms inline) ----------------
__global__ __launch_bounds__(256) void loss_kernel(const float* __restrict__ es,
                                                   float* __restrict__ loss_part) {
    int m = blockIdx.x, t = threadIdx.x;
    __shared__ float esm[2048];
    __shared__ float sml[16];
    for (int i = t; i < 2048; i += 256) esm[i] = es[m * 2048 + i];
    __syncthreads();
    if (t < 16) {
        float s = 0.f;
        const float* r = esm + t * 128;
        for (int c = 0; c < 128; ++c) s += r[c] * r[c];
        sml[t] = s;
    }
    __syncthreads();
    int n = t >> 2, bq = t & 3;
    float part = 0.f;
#pragma unroll
    for (int u = 0; u < 4; u++) {
        int b = bq * 4 + u;
        float inner = 0.f, sn = 0.f;
        const float* er = es + n * 2048 + b * 128;
        const float* em = esm + b * 128;
        for (int c = 0; c < 128; c += 4) {
            float4 a = *(const float4*)(em + c);
            float4 o = *(const float4*)(er + c);
            inner += a.x * o.x + a.y * o.y + a.z * o.z + a.w * o.w;
            sn += o.x * o.x + o.y * o.y + o.z * o.z + o.w * o.w;
        }
        float sm = sml[b];
        float cosv = inner / (sqrtf(sm) * sqrtf(sn));
        float d2 = sm + sn - 2.f * inner;
        float dist = sqrtf(fmaxf(d2, 0.f));
        part += cosv * dist + (1.f - cosv) * fmaxf(MARGIN - dist, 0.f);
    }
    part += __shfl_xor(part, 1, 64);
    part += __shfl_xor(part, 2, 64);
    float labs = fabsf(part * (1.f / 16.f));
    __shared__ float pl[64];
    if (bq == 0) pl[n] = labs;
    __syncthreads();
    if (t < 64) {
        float v = pl[t];
        for (int k = 1; k < 64; k <<= 1) v += __shfl_xor(v, k, 64);
        if (t == 0) loss_part[m] = v;
    }
}

// ---------------- alpha softmax + Wa/Wb scatter ----------------
__global__ __launch_bounds__(256) void alpha_wab(const int* __restrict__ off_n,
                                                 const int* __restrict__ gedge_n,
                                                 const float* __restrict__ p,
                                                 const float* __restrict__ q,
                                                 const int* __restrict__ deg_m,
                                                 float* __restrict__ Wa,
                                                 float* __restrict__ Wb) {
    int idx = blockIdx.x * 256 + threadIdx.x;  // 65536 = N*B
    int b = idx & 15, n = idx >> 4;
    int beg = off_n[n], end = off_n[n + 1];
    if (beg == end) return;
    float pb = p[n * 16 + b];
    float lf = pb + q[gedge_n[beg] * 16 + b];
    lf = lf >= 0.f ? lf : NEG_SLOPE * lf;
    float ssum = 0.f;
    for (int i = beg; i < end; i++) {
        float lg = pb + q[gedge_n[i] * 16 + b];
        lg = lg >= 0.f ? lg : NEG_SLOPE * lg;
        ssum += __expf(lg - lf);
    }
    float inv = 1.f / ssum;
    for (int i = beg; i < end; i++) {
        int m = gedge_n[i];
        float lg = pb + q[m * 16 + b];
        lg = lg >= 0.f ? lg : NEG_SLOPE * lg;
        float a = __expf(lg - lf) * inv;
        float bninv = 1.f / (float)deg_m[m];
        atomicAdd(&Wa[((size_t)b * 64 + m) * 4096 + n], a);
        atomicAdd(&Wb[((size_t)b * 4096 + n) * 64 + m], a * bninv);
    }
}

// ---------------- ouT GEMM (K-split): ouT[slot][m] += sum_n xwT[slot][n]*Wa[b][m][n] --
__global__ __launch_bounds__(256) void oute_gemm(const unsigned short* __restrict__ xwTh,
                                                 const unsigned short* __restrict__ xwTl,
                                                 const float* __restrict__ Wa,
                                                 float* __restrict__ ouT) {
    int t = threadIdx.x, w = t >> 6, l = t & 63;
    int lrow = l & 15, lk = l >> 4;
    int slot0 = blockIdx.x * 64;
    int b = slot0 >> 7;
    int kbase = blockIdx.y * (4096 / NCH);
    f32x4 acc[4];
#pragma unroll
    for (int tj = 0; tj < 4; ++tj) acc[tj] = (f32x4){0.f, 0.f, 0.f, 0.f};
    int srow = slot0 + w * 16 + lrow;
    const unsigned short* xh = xwTh + (size_t)srow * 4096;
    const unsigned short* xl = xwTl + (size_t)srow * 4096;
    const float* wab = Wa + (size_t)b * 64 * 4096;
#pragma unroll 2
    for (int ks = 0; ks < 4096 / NCH / 32; ++ks) {
        int n0 = kbase + ks * 32 + lk * 8;
        bfrag ah = *(const bfrag*)(xh + n0);
        bfrag al = *(const bfrag*)(xl + n0);
#pragma unroll
        for (int tj = 0; tj < 4; ++tj) {
            int mcol = tj * 16 + lrow;
            bfrag wh, wl_;
            split8(wab + (size_t)mcol * 4096 + n0, wh, wl_);
            acc[tj] = __builtin_amdgcn_mfma_f32_16x16x32_bf16(ah, wh, acc[tj], 0, 0, 0);
            acc[tj] = __builtin_amdgcn_mfma_f32_16x16x32_bf16(ah, wl_, acc[tj], 0, 0, 0);
            acc[tj] = __builtin_amdgcn_mfma_f32_16x16x32_bf16(al, wh, acc[tj], 0, 0, 0);
        }
    }
#pragma unroll
    for (int tj = 0; tj < 4; ++tj) {
        int mcol = tj * 16 + lrow;
#pragma unroll
        for (int reg = 0; reg < 4; ++reg) {
            int slot = slot0 + w * 16 + lk * 4 + reg;
            atomicAdd(&ouT[slot * 64 + mcol], acc[tj][reg]);
        }
    }
}

// ---------------- out GEMM: out[b][n][c] = D[n]*sum_m Wb[b][n][m]*ouT[b*128+c][m] -----
__global__ __launch_bounds__(256) void out_gemm(const float* __restrict__ Wb,
                                                const float* __restrict__ ouT,
                                                const int* __restrict__ deg_n,
                                                float* __restrict__ out) {
    int t = threadIdx.x, w = t >> 6, l = t & 63;
    int lrow = l & 15, lk = l >> 4;
    int nbase = blockIdx.x * 128 + w * 32;
    int b = blockIdx.y;
    f32x4 acc[2][8];
#pragma unroll
    for (int ti = 0; ti < 2; ++ti)
#pragma unroll
        for (int tj = 0; tj < 8; ++tj) acc[ti][tj] = (f32x4){0.f, 0.f, 0.f, 0.f};
#pragma unroll
    for (int ks = 0; ks < 2; ++ks) {
        int m0 = ks * 32 + lk * 8;
        bfrag wh[2], wl[2];
#pragma unroll
        for (int ti = 0; ti < 2; ++ti) {
            int nr = nbase + ti * 16 + lrow;
            split8(Wb + ((size_t)b * 4096 + nr) * 64 + m0, wh[ti], wl[ti]);
        }
#pragma unroll
        for (int tj = 0; tj < 8; ++tj) {
            int slot = b * 128 + tj * 16 + lrow;
            bfrag oh, ol;
            split8(ouT + (size_t)slot * 64 + m0, oh, ol);
#pragma unroll
            for (int ti = 0; ti < 2; ++ti) {
                acc[ti][tj] = __builtin_amdgcn_mfma_f32_16x16x32_bf16(wh[ti], oh, acc[ti][tj], 0, 0, 0);
                acc[ti][tj] = __builtin_amdgcn_mfma_f32_16x16x32_bf16(wh[ti], ol, acc[ti][tj], 0, 0, 0);
                acc[ti][tj] = __builtin_amdgcn_mfma_f32_16x16x32_bf16(wl[ti], oh, acc[ti][tj], 0, 0, 0);
            }
        }
    }
#pragma unroll
    for (int ti = 0; ti < 2; ++ti) {
#pragma unroll
        for (int reg = 0; reg < 4; ++reg) {
            int n = nbase + ti * 16 + lk * 4 + reg;
            float d = (float)deg_n[n];
#pragma unroll
            for (int tj = 0; tj < 8; ++tj) {
                out[(size_t)b * 524288 + (size_t)n * 128 + tj * 16 + lrow] = d * acc[ti][tj][reg];
            }
        }
    }
}

// ---------------- finalize scalar ----------------
__global__ __launch_bounds__(256) void finalize_kernel(const int* __restrict__ deg_n,
                                                       const float* __restrict__ S1,
                                                       const int* __restrict__ deg_m,
                                                       const float* __restrict__ T,
                                                       const float* __restrict__ loss_part,
                                                       float* __restrict__ out_scalar) {
    int t = threadIdx.x;
    double a = 0.0;
    for (int n = t; n < 4096; n += 256) a += (double)deg_n[n] * (double)S1[n];
    double bsum = 0.0, lsum = 0.0;
    if (t < 64) {
        bsum = (double)deg_m[t] * (double)T[t];
        lsum = (double)loss_part[t];
    }
    __shared__ double sa[256], sb[256], sl[256];
    sa[t] = a; sb[t] = bsum; sl[t] = lsum;
    __syncthreads();
    for (int s = 128; s > 0; s >>= 1) {
        if (t < s) { sa[t] += sa[t + s]; sb[t] += sb[t + s]; sl[t] += sl[t + s]; }
        __syncthreads();
    }
    if (t == 0) {
        double mean = (sa[0] - sb[0]) / 25165824.0;  // E*B*C
        out_scalar[0] = (float)(fabs(mean) + sl[0] / 4225.0);
    }
}

extern "C" void kernel_launch(void* const* d_in, const int* in_sizes, int n_in,
                              void* d_out, int out_size, void* d_ws, size_t ws_size,
                              hipStream_t stream) {
    const float* x = (const float*)d_in[0];
    const int* nodes = (const int*)d_in[1];
    const int* edges = (const int*)d_in[2];
    const float* w = (const float*)d_in[3];
    const float* att = (const float*)d_in[4];
    float* out = (float*)d_out;

    char* ws = (char*)d_ws;
    size_t o = 0;
    unsigned short* xwTh = (unsigned short*)(ws + o); o += (size_t)2048 * 4096 * 2;  // 16 MB
    unsigned short* xwTl = (unsigned short*)(ws + o); o += (size_t)2048 * 4096 * 2;  // 16 MB
    // ---- zero region (one memset): Acnt, Wa, Wb, ouT, es, deg_n, deg_m, S1, q, T ----
    size_t zbase = o;
    float* Acnt = (float*)(ws + o);  o += (size_t)Mm * Nn * 4;            // 1 MB
    float* Wa = (float*)(ws + o);    o += (size_t)Bc * Mm * Nn * 4;       // 16 MB
    float* Wb = (float*)(ws + o);    o += (size_t)Bc * Nn * Mm * 4;       // 16 MB
    float* ouT = (float*)(ws + o);   o += (size_t)2048 * 64 * 4;          // 512 KB
    float* es = (float*)(ws + o);    o += (size_t)Mm * 2048 * 4;          // 512 KB
    int* deg_n = (int*)(ws + o);     o += (size_t)Nn * 4;
    int* deg_m = (int*)(ws + o);     o += (size_t)Mm * 4;
    float* S1 = (float*)(ws + o);    o += (size_t)Nn * 4;
    float* q = (float*)(ws + o);     o += (size_t)Mm * Bc * 4;
    float* T = (float*)(ws + o);     o += (size_t)Mm * 4;
    size_t zlen = o - zbase;
    // ---- end zero region ----
    float* p = (float*)(ws + o);         o += (size_t)Nn * Bc * 4;        // 256 KB
    float* loss_part = (float*)(ws + o); o += (size_t)Mm * 4;
    int* off_n = (int*)(ws + o);         o += (size_t)(Nn + 1) * 4;
    int* cur_n = (int*)(ws + o);         o += (size_t)Nn * 4;
    int* gedge_n = (int*)(ws + o);       o += (size_t)Ee * 4;
    unsigned short* wsplit = (unsigned short*)(ws + o); o += 65536;       // 64 KB

    hipMemsetAsync(ws + zbase, 0, zlen, stream);

    prep_kernel<<<112, 256, 0, stream>>>(w, nodes, edges, wsplit, deg_n, deg_m, Acnt);
    gemm_xw<<<512, 256, 0, stream>>>(x, wsplit, att, xwTh, xwTl, p, S1);
    scan_kernel<<<1, 1024, 0, stream>>>(deg_n, off_n, cur_n);
    fill_kernel<<<48, 256, 0, stream>>>(nodes, edges, cur_n, gedge_n);
    es_gemm<<<dim3(32, NCH), 256, 0, stream>>>(Acnt, xwTh, xwTl, att, es, q, T);
    loss_kernel<<<Mm, 256, 0, stream>>>(es, loss_part);
    alpha_wab<<<256, 256, 0, stream>>>(off_n, gedge_n, p, q, deg_m, Wa, Wb);
    oute_gemm<<<dim3(32, NCH), 256, 0, stream>>>(xwTh, xwTl, Wa, ouT);
    out_gemm<<<dim3(32, 16), 256, 0, stream>>>(Wb, ouT, deg_n, out);
    finalize_kernel<<<1, 256, 0, stream>>>(deg_n, S1, deg_m, T, loss_part, out + (size_t)Bc * Nn * Cc);
}